// Round 5
// baseline (654.403 us; speedup 1.0000x reference)
//
#include <hip/hip_runtime.h>
#include <hip/hip_bf16.h>
#include <math.h>

#define PI_F 3.14159265358979323846f
#define R0_F 5.0f

// ---------------------------------------------------------------------------
// ws layout:
//   P[n][816] float : per-node input projections
//     [0,48)    Pa[k*16+r]                 k=0:pa000,1:pa011,2:pa022
//     [48,240)  Pv[48+k*48+3r+i]           k=0:pv101,1:pv110,2:pv112,3:pv121
//     [240,816) Pd[240+k*144+9r+ij]        k=0:pd202,1:pd211,2:pd220,3:pd222
//   counts[N] | offs[N+1] | cursor[N] | eidx[E]   (ints, CSR by src)
// ---------------------------------------------------------------------------

static __device__ __forceinline__ float dot4(float4 a, float4 b) {
  return a.x * b.x + a.y * b.y + a.z * b.z + a.w * b.w;
}

// ------------------- K1: per-node input projections (register-tiled) -------
// G nodes per block; x staged TRANSPOSED in LDS so the d-reduction is
// contiguous (ds_read_b128); weight row-pairs in registers reused across
// all outputs of the pair; 2-18 independent accumulators for ILP.
#define G 4
__global__ __launch_bounds__(256) void node_proj_kernel(
    const float* __restrict__ x_a, const float* __restrict__ x_v, const float* __restrict__ x_d,
    const float* __restrict__ W1_a, const float* __restrict__ W1_v, const float* __restrict__ W1_d,
    float* __restrict__ P, int N)
{
  const int tid = threadIdx.x;
  const int n0 = blockIdx.x * G;
  // per node: xa[0,128) | xvT[128 + i*64 + d] | xdT[320 + ij*32 + d]
  __shared__ __align__(16) float sx[G][608];

  #pragma unroll
  for (int g = 0; g < G; g++) {
    int n = n0 + g;
    if (n >= N) break;
    const float* xa = x_a + (size_t)n * 128;
    const float* xv = x_v + (size_t)n * 192;
    const float* xd = x_d + (size_t)n * 288;
    if (tid < 128) sx[g][tid] = xa[tid];
    if (tid < 192) { int d = tid / 3, i = tid - 3 * d; sx[g][128 + i * 64 + d] = xv[tid]; }
    for (int m = tid; m < 288; m += 256) {
      int d = m / 9, ij = m - 9 * d;
      sx[g][320 + ij * 32 + d] = xd[m];
    }
  }
  __syncthreads();

  // task list (type-major): [0,96) A-pairs, [96,224) V-pairs, [224,352) D-pairs
  for (int task = tid; task < 352; task += 256) {
    int g, pr;
    const float* xg;
    float* Pn;
    if (task < 96) {
      g = task / 24; pr = task - 24 * g;
      if (n0 + g >= N) continue;
      xg = sx[g]; Pn = P + (size_t)(n0 + g) * 816;
      int row0 = pr * 2;
      const float4* w0 = (const float4*)(W1_a + row0 * 128);
      const float4* w1 = w0 + 32;
      const float4* xq = (const float4*)xg;
      float a0 = 0.0f, a1 = 0.0f;
      #pragma unroll
      for (int k = 0; k < 32; k++) {
        float4 x4 = xq[k];
        a0 += dot4(w0[k], x4); a1 += dot4(w1[k], x4);
      }
      Pn[row0] = a0; Pn[row0 + 1] = a1;
    } else if (task < 224) {
      int idx = task - 96;
      g = idx >> 5; pr = idx & 31;
      if (n0 + g >= N) continue;
      xg = sx[g]; Pn = P + (size_t)(n0 + g) * 816;
      int row0 = pr * 2;
      const float4* w0 = (const float4*)(W1_v + row0 * 64);
      const float4* w1 = w0 + 16;
      const float4* x0 = (const float4*)(xg + 128);
      const float4* x1 = (const float4*)(xg + 192);
      const float4* x2 = (const float4*)(xg + 256);
      float a00 = 0, a01 = 0, a02 = 0, a10 = 0, a11 = 0, a12 = 0;
      #pragma unroll
      for (int k = 0; k < 16; k++) {
        float4 w0k = w0[k], w1k = w1[k];
        float4 xv0 = x0[k], xv1 = x1[k], xv2 = x2[k];
        a00 += dot4(w0k, xv0); a01 += dot4(w0k, xv1); a02 += dot4(w0k, xv2);
        a10 += dot4(w1k, xv0); a11 += dot4(w1k, xv1); a12 += dot4(w1k, xv2);
      }
      int k0 = row0 >> 4, r0 = row0 & 15;
      int row1 = row0 + 1, k1 = row1 >> 4, r1 = row1 & 15;
      float* b0 = Pn + 48 + k0 * 48 + 3 * r0;
      float* b1 = Pn + 48 + k1 * 48 + 3 * r1;
      b0[0] = a00; b0[1] = a01; b0[2] = a02;
      b1[0] = a10; b1[1] = a11; b1[2] = a12;
    } else {
      int idx = task - 224;
      g = idx >> 5; pr = idx & 31;
      if (n0 + g >= N) continue;
      xg = sx[g]; Pn = P + (size_t)(n0 + g) * 816;
      int row0 = pr * 2;
      const float4* w0 = (const float4*)(W1_d + row0 * 32);
      const float4* w1 = w0 + 8;
      float a0[9], a1[9];
      #pragma unroll
      for (int ij = 0; ij < 9; ij++) { a0[ij] = 0.0f; a1[ij] = 0.0f; }
      #pragma unroll
      for (int k = 0; k < 8; k++) {
        float4 w0k = w0[k], w1k = w1[k];
        #pragma unroll
        for (int ij = 0; ij < 9; ij++) {
          float4 x4 = ((const float4*)(xg + 320 + ij * 32))[k];
          a0[ij] += dot4(w0k, x4); a1[ij] += dot4(w1k, x4);
        }
      }
      int k0 = row0 >> 4, r0 = row0 & 15;
      int row1 = row0 + 1, k1 = row1 >> 4, r1 = row1 & 15;
      float* b0 = Pn + 240 + k0 * 144 + 9 * r0;
      float* b1 = Pn + 240 + k1 * 144 + 9 * r1;
      #pragma unroll
      for (int ij = 0; ij < 9; ij++) { b0[ij] = a0[ij]; b1[ij] = a1[ij]; }
    }
  }
}

// ------------------- CSR build ---------------------------------------------
__global__ void hist_kernel(const int* __restrict__ src, int* __restrict__ counts, int E) {
  int e = blockIdx.x * 256 + threadIdx.x;
  if (e < E) atomicAdd(&counts[src[e]], 1);
}

__global__ __launch_bounds__(1024) void scan_kernel(
    const int* __restrict__ counts, int* __restrict__ offs, int* __restrict__ cursor,
    int N, int E)
{
  __shared__ int part[1024];
  int tid = threadIdx.x;
  int chunk = (N + 1023) / 1024;
  int lo = tid * chunk, hi = min(lo + chunk, N);
  int s = 0;
  for (int i = lo; i < hi; i++) s += counts[i];
  part[tid] = s;
  __syncthreads();
  for (int off = 1; off < 1024; off <<= 1) {
    int v = (tid >= off) ? part[tid - off] : 0;
    __syncthreads();
    part[tid] += v;
    __syncthreads();
  }
  int run = part[tid] - s;  // exclusive prefix of this thread's chunk
  for (int i = lo; i < hi; i++) { offs[i] = run; cursor[i] = run; run += counts[i]; }
  if (tid == 0) offs[N] = E;
}

__global__ void scatter_kernel(const int* __restrict__ src, int* __restrict__ cursor,
                               int* __restrict__ eidx, int E) {
  int e = blockIdx.x * 256 + threadIdx.x;
  if (e < E) { int p = atomicAdd(&cursor[src[e]], 1); eidx[p] = e; }
}

// ------------------- K2: one wave per node, atomic-free ---------------------
// LDS float map (1280):
//   [0,816)    sP  (gathered P[dst] for current edge)
//   [816,992)  sq  (q[i*16+r], 176)
//   [992,996)  rvtab: rv0,rv1,rv2,1.0
//   [996,1005) outer[ij] = rv_i*rv_j
//   [1008,1264) edge meta float4[64]: (r0,r1,r2, dst-as-float-bits)
// Epilogue reuses [0,960) as ACC:
//   [0,48) A_a[k*16+r]; [48,240) A_v[48+k*48+j*16+r];
//   [240,960) S[240 + s*180 + ij*20 + r]   (row stride 20 breaks bank aliasing)
__global__ __launch_bounds__(64, 3) void node_gather_kernel(
    const float* __restrict__ r_ij, const int* __restrict__ dst,
    const int* __restrict__ offs, const int* __restrict__ eidx,
    const float* __restrict__ Pg, const float* __restrict__ W2,
    const float* __restrict__ Wo_a, const float* __restrict__ Wo_v, const float* __restrict__ Wo_d,
    float* __restrict__ out, int N)
{
  __shared__ __align__(16) float S[1280];
  float4* S4 = (float4*)S;
  const int n = blockIdx.x, lane = threadIdx.x;
  const int off = offs[n], deg = offs[n + 1] - off;

  // ---- per-lane slot constants (V slots p=0..2, D slots p=3..11) ----
  int aP[12], aQ[12], aF[12];
  unsigned typm = 0;  // bit p set => dot3-with-rv form
  #pragma unroll
  for (int p = 0; p < 3; p++) {
    int t = lane + 64 * p;                 // < 192 always
    int k = t / 48, m = t - 48 * k, jj = m >> 4, r = m & 15;
    int q_ = 816 + (3 + k) * 16 + r;       // q3..q6
    int P_, F_;
    if (k == 0)      { P_ = 16 + r;              F_ = 992 + jj; }
    else if (k == 1) { P_ = 48 + 3 * r + jj;     F_ = 995; }
    else if (k == 2) { P_ = 192 + 3 * r;         F_ = 992 + jj; typm |= 1u << p; }
    else             { P_ = 384 + 9 * r + 3 * jj; F_ = 995;     typm |= 1u << p; }
    aP[p] = P_; aQ[p] = q_; aF[p] = F_;
  }
  #pragma unroll
  for (int p = 0; p < 9; p++) {
    int u = lane + 64 * p;                 // < 576 always
    int s = u / 144, m = u - 144 * s, ij = m >> 4, r = m & 15;
    int i = ij / 3, jj = ij - 3 * i;
    int P_, F_, q_;
    if (s == 0)      { P_ = 32 + r;              q_ = 112 + r; F_ = 996 + ij; }
    else if (s == 1) { P_ = 144 + 3 * r + i;     q_ = 128 + r; F_ = 992 + jj; }
    else if (s == 2) { P_ = 240 + 9 * r + ij;    q_ = 144 + r; F_ = 995; }
    else             { P_ = 672 + 9 * r + 3 * i; q_ = 160 + r; F_ = 992 + jj; typm |= 1u << (3 + p); }
    aP[3 + p] = P_; aQ[3 + p] = 816 + q_; aF[3 + p] = F_;
  }
  const int ak = lane >> 4, ar = lane & 15;   // A slot (lane<48)

  // ---- hoist W2 rows for this lane's q slots ----
  float4 wqa[3], wqb[3];
  #pragma unroll
  for (int p = 0; p < 3; p++) {
    int tq = lane + 64 * p; if (tq > 175) tq = 175;
    const float4* w = (const float4*)(W2 + tq * 8);
    wqa[p] = w[0]; wqb[p] = w[1];
  }

  float accA = 0.0f, acc[12];
  #pragma unroll
  for (int p = 0; p < 12; p++) acc[p] = 0.0f;

  float4 pb0 = {}, pb1 = {}, pb2 = {}, pb3 = {};
  const int l3 = 192 + (lane < 12 ? lane : 0);

  for (int base = 0; base < deg; base += 64) {
    int cnt = min(deg - base, 64);
    __syncthreads();
    if (lane < cnt) {
      int e = eidx[off + base + lane];
      float a = r_ij[3 * (size_t)e], b = r_ij[3 * (size_t)e + 1], c = r_ij[3 * (size_t)e + 2];
      S4[252 + lane] = make_float4(a, b, c, __int_as_float(dst[e]));
    }
    __syncthreads();
    // preload edge 0 of this chunk
    {
      float4 me = S4[252];
      if (me.x * me.x + me.y * me.y + me.z * me.z < 5.0f) {
        const float4* Pp = (const float4*)(Pg + (size_t)__float_as_int(me.w) * 816);
        pb0 = Pp[lane]; pb1 = Pp[64 + lane]; pb2 = Pp[128 + lane]; pb3 = Pp[l3];
      }
    }
    for (int t = 0; t < cnt; t++) {
      float4 me = S4[252 + t];
      float r0 = me.x, r1 = me.y, r2 = me.z;
      float rr = r0 * r0 + r1 * r1 + r2 * r2;
      bool live = rr < 5.0f;
      float rv0 = 0, rv1 = 0, rv2 = 0;
      if (live) {
        float x_sq = rr * (1.0f / R0_F);
        float env = 1.0f - x_sq;
        // rv
        float v0 = r0 * (17.0f / R0_F), v1 = r1 * (17.0f / R0_F), v2 = r2 * (17.0f / R0_F);
        float nn = sqrtf(v0 * v0 + v1 * v1 + v2 * v2);
        float sig = 2.0f / (1.0f + __expf(-nn)) - 1.0f;
        float sc = sig / (nn + 1e-6f);
        rv0 = v0 * sc; rv1 = v1 * sc; rv2 = v2 * sc;
        // radial basis: cos(k*th)*env via Chebyshev
        float rad[8];
        {
          float c1 = __cosf(PI_F * sqrtf(x_sq));
          float two_c1 = 2.0f * c1, cm2 = 1.0f, cm1 = c1;
          rad[0] = env; rad[1] = c1 * env;
          #pragma unroll
          for (int k = 2; k < 8; k++) { float c = two_c1 * cm1 - cm2; rad[k] = c * env; cm2 = cm1; cm1 = c; }
        }
        float4 ra = make_float4(rad[0], rad[1], rad[2], rad[3]);
        float4 rb = make_float4(rad[4], rad[5], rad[6], rad[7]);
        // stage sP from prefetch regs
        S4[lane] = pb0; S4[64 + lane] = pb1; S4[128 + lane] = pb2;
        if (lane < 12) S4[192 + lane] = pb3;
        // q values
        S[816 + lane] = dot4(wqa[0], ra) + dot4(wqb[0], rb);
        S[880 + lane] = dot4(wqa[1], ra) + dot4(wqb[1], rb);
        if (lane < 48) S[944 + lane] = dot4(wqa[2], ra) + dot4(wqb[2], rb);
        // tables
        if (lane < 4) S[992 + lane] = (lane == 0) ? rv0 : (lane == 1) ? rv1 : (lane == 2) ? rv2 : 1.0f;
        if (lane >= 4 && lane < 13) {
          int ij = lane - 4, i = ij / 3, j = ij - 3 * i;
          float a = (i == 0) ? rv0 : (i == 1) ? rv1 : rv2;
          float b = (j == 0) ? rv0 : (j == 1) ? rv1 : rv2;
          S[992 + lane] = a * b;   // outer[ij] at 996+ij
        }
      }
      // prefetch next edge's P row (overlaps with accumulation)
      if (t + 1 < cnt) {
        float4 m2 = S4[252 + t + 1];
        if (m2.x * m2.x + m2.y * m2.y + m2.z * m2.z < 5.0f) {
          const float4* Pp = (const float4*)(Pg + (size_t)__float_as_int(m2.w) * 816);
          pb0 = Pp[lane]; pb1 = Pp[64 + lane]; pb2 = Pp[128 + lane]; pb3 = Pp[l3];
        }
      }
      __syncthreads();
      if (live) {
        // A slot
        if (lane < 48) {
          float v;
          if (ak == 0)      v = S[ar] * S[816 + ar];
          else if (ak == 1) v = (S[96 + 3 * ar] * rv0 + S[97 + 3 * ar] * rv1 + S[98 + 3 * ar] * rv2) * S[832 + ar];
          else {
            int b = 528 + 9 * ar;
            float o = (S[b] * rv0 + S[b + 3] * rv1 + S[b + 6] * rv2) * rv0
                    + (S[b + 1] * rv0 + S[b + 4] * rv1 + S[b + 7] * rv2) * rv1
                    + (S[b + 2] * rv0 + S[b + 5] * rv1 + S[b + 8] * rv2) * rv2;
            v = o * S[848 + ar];
          }
          accA += v;
        }
        // V + D slots, unified form
        #pragma unroll
        for (int p = 0; p < 12; p++) {
          float pv;
          if (typm & (1u << p)) pv = S[aP[p]] * rv0 + S[aP[p] + 1] * rv1 + S[aP[p] + 2] * rv2;
          else                  pv = S[aP[p]];
          acc[p] += pv * S[aQ[p]] * S[aF[p]];
        }
      }
      __syncthreads();
    }
  }

  // ---------------- epilogue: rank->channel, write out ----------------
  __syncthreads();
  if (lane < 48) S[lane] = accA;
  #pragma unroll
  for (int p = 0; p < 3; p++) S[48 + lane + 64 * p] = acc[p];
  #pragma unroll
  for (int p = 0; p < 9; p++) {
    int u = lane + 64 * p;
    int s = u / 144, m = u - 144 * s, ij = m >> 4, r = m & 15;
    S[240 + s * 180 + ij * 20 + r] = acc[3 + p];
  }
  __syncthreads();

  const size_t baseV = (size_t)N * 128;
  const size_t baseD = (size_t)N * 320;

  // B_a
  #pragma unroll
  for (int h = 0; h < 2; h++) {
    int c = lane + 64 * h;
    float a_ = 0.0f;
    #pragma unroll
    for (int k = 0; k < 3; k++) {
      const float4* w = (const float4*)(Wo_a + k * 2048 + c * 16);
      const float4* A4 = (const float4*)(&S[k * 16]);
      #pragma unroll
      for (int cc = 0; cc < 4; cc++) a_ += dot4(w[cc], A4[cc]);
    }
    out[(size_t)n * 128 + c] = a_;
  }
  // B_v (d = lane)
  {
    float o0 = 0, o1 = 0, o2 = 0;
    #pragma unroll
    for (int k = 0; k < 4; k++) {
      const float4* w = (const float4*)(Wo_v + k * 1024 + lane * 16);
      float4 w0 = w[0], w1 = w[1], w2 = w[2], w3 = w[3];
      #pragma unroll
      for (int j = 0; j < 3; j++) {
        const float4* A4 = (const float4*)(&S[48 + k * 48 + j * 16]);
        float v = dot4(w0, A4[0]) + dot4(w1, A4[1]) + dot4(w2, A4[2]) + dot4(w3, A4[3]);
        if (j == 0) o0 += v; else if (j == 1) o1 += v; else o2 += v;
      }
    }
    size_t ov = baseV + (size_t)n * 192 + lane * 3;
    out[ov] = o0; out[ov + 1] = o1; out[ov + 2] = o2;
  }
  // B_d
  #pragma unroll
  for (int p = 0; p < 5; p++) {
    int t = lane + 64 * p;
    if (t < 288) {
      int d = t / 9, ij = t - 9 * d;
      float a_ = 0.0f;
      #pragma unroll
      for (int s = 0; s < 4; s++) {
        const float4* w = (const float4*)(Wo_d + s * 512 + d * 16);
        const float4* A4 = (const float4*)(&S[240 + s * 180 + ij * 20]);
        a_ += dot4(w[0], A4[0]) + dot4(w[1], A4[1]) + dot4(w[2], A4[2]) + dot4(w[3], A4[3]);
      }
      out[baseD + (size_t)n * 288 + t] = a_;
    }
  }
}

// ---------------------------------------------------------------------------
extern "C" void kernel_launch(void* const* d_in, const int* in_sizes, int n_in,
                              void* d_out, int out_size, void* d_ws, size_t ws_size,
                              hipStream_t stream) {
  const float* r_ij = (const float*)d_in[0];
  const float* x_a  = (const float*)d_in[1];
  const float* x_v  = (const float*)d_in[2];
  const float* x_d  = (const float*)d_in[3];
  const float* W1_a = (const float*)d_in[4];
  const float* W1_v = (const float*)d_in[5];
  const float* W1_d = (const float*)d_in[6];
  const float* W2   = (const float*)d_in[7];
  const float* Wo_a = (const float*)d_in[8];
  const float* Wo_v = (const float*)d_in[9];
  const float* Wo_d = (const float*)d_in[10];
  const int*  src   = (const int*)d_in[11];
  const int*  dst   = (const int*)d_in[12];

  const int E = in_sizes[0] / 3;
  const int N = in_sizes[1] / 128;

  float* P    = (float*)d_ws;
  int* counts = (int*)(P + (size_t)N * 816);
  int* offs   = counts + N;
  int* cursor = offs + N + 1;
  int* eidx   = cursor + N;

  hipMemsetAsync(counts, 0, sizeof(int) * (size_t)N, stream);

  hist_kernel<<<(E + 255) / 256, 256, 0, stream>>>(src, counts, E);
  scan_kernel<<<1, 1024, 0, stream>>>(counts, offs, cursor, N, E);
  scatter_kernel<<<(E + 255) / 256, 256, 0, stream>>>(src, cursor, eidx, E);
  node_proj_kernel<<<(N + G - 1) / G, 256, 0, stream>>>(x_a, x_v, x_d, W1_a, W1_v, W1_d, P, N);
  node_gather_kernel<<<N, 64, 0, stream>>>(r_ij, dst, offs, eidx, P, W2,
                                           Wo_a, Wo_v, Wo_d, (float*)d_out, N);
}

// Round 6
// 647.850 us; speedup vs baseline: 1.0101x; 1.0101x over previous
//
#include <hip/hip_runtime.h>
#include <hip/hip_bf16.h>
#include <math.h>

#define PI_F 3.14159265358979323846f
#define R0_F 5.0f

typedef short sh8 __attribute__((ext_vector_type(8)));
typedef float f32x4 __attribute__((ext_vector_type(4)));

// ---------------------------------------------------------------------------
// ws layout (in order):
//   P[n][816] f32 : per-node input projections  (NEW inner layout)
//     [0,48)    Pa[k*16+r]                   k=0:pa000,1:pa011,2:pa022
//     [48,240)  Pv[48 + i*64 + k*16 + r]     k=0:pv101,1:pv110,2:pv112,3:pv121
//     [240,816) Pd[240 + ij*64 + k*16 + r]   k=0:pd202,1:pd211,2:pd220,3:pd222
//   xa_bf[N*128] u16 | xv_bf[3][N*64] | xd_bf[9][N*32] | w_bf[12288]
//   counts[N] | offs[N+1] | cursor[N] | eidx[E]  (ints, CSR by src)
// ---------------------------------------------------------------------------

static __device__ __forceinline__ float dot4(float4 a, float4 b) {
  return a.x * b.x + a.y * b.y + a.z * b.z + a.w * b.w;
}
static __device__ __forceinline__ unsigned short f2bf(float f) {
  union { __hip_bfloat16 h; unsigned short u; } c; c.h = __float2bfloat16(f); return c.u;
}

// ------------------- repack kernels (f32 -> bf16 GEMM buffers) --------------
__global__ __launch_bounds__(256) void repack_aw_kernel(
    const float* __restrict__ x_a, const float* __restrict__ W1_a,
    const float* __restrict__ W1_v, const float* __restrict__ W1_d,
    unsigned short* __restrict__ xa, unsigned short* __restrict__ wbuf, int N)
{
  int t = blockIdx.x * 256 + threadIdx.x;
  int na = N * 128;
  if (t < na) { xa[t] = f2bf(x_a[t]); return; }
  int u = t - na;
  if (u < 6144) wbuf[u] = f2bf(W1_a[u]);                 // wa[48][128]
  else if (u < 10240) wbuf[u] = f2bf(W1_v[u - 6144]);    // wv[64][64]
  else if (u < 12288) wbuf[u] = f2bf(W1_d[u - 10240]);   // wd[64][32]
}

__global__ __launch_bounds__(256) void repack_xv_kernel(
    const float* __restrict__ x_v, unsigned short* __restrict__ xv, int N)
{
  int t = blockIdx.x * 256 + threadIdx.x;
  int i = blockIdx.y;
  if (t < N * 64) {
    int n = t >> 6, d = t & 63;
    xv[(size_t)i * N * 64 + t] = f2bf(x_v[(size_t)n * 192 + d * 3 + i]);
  }
}

__global__ __launch_bounds__(256) void repack_xd_kernel(
    const float* __restrict__ x_d, unsigned short* __restrict__ xd, int N)
{
  int t = blockIdx.x * 256 + threadIdx.x;
  int ij = blockIdx.y;
  if (t < N * 32) {
    int n = t >> 5, d = t & 31;
    xd[(size_t)ij * N * 32 + t] = f2bf(x_d[(size_t)n * 288 + d * 9 + ij]);
  }
}

// ------------------- K1: MFMA projection (13 GEMM segments) -----------------
// seg 0: A (K=128,NT=3,out 0); seg 1..3: V_i (K=64,NT=4,out 48+i*64);
// seg 4..12: D_ij (K=32,NT=4,out 240+ij*64).
// Wave handles 64 nodes (4 M-tiles) x all N-tiles of its segment.
__global__ __launch_bounds__(64) void mfma_proj_kernel(
    const unsigned short* __restrict__ xa, const unsigned short* __restrict__ xv,
    const unsigned short* __restrict__ xd, const unsigned short* __restrict__ wbuf,
    float* __restrict__ P, int N)
{
  const int seg = blockIdx.y;
  const int mbase = blockIdx.x * 64;
  const int lane = threadIdx.x;
  const int col = lane & 15, quad = lane >> 4;

  const unsigned short* X; const unsigned short* W;
  int K, NT, outbase;
  if (seg == 0)      { X = xa; W = wbuf; K = 128; NT = 3; outbase = 0; }
  else if (seg < 4)  { int i = seg - 1;  X = xv + (size_t)i * N * 64;  W = wbuf + 6144;  K = 64; NT = 4; outbase = 48 + i * 64; }
  else               { int ij = seg - 4; X = xd + (size_t)ij * N * 32; W = wbuf + 10240; K = 32; NT = 4; outbase = 240 + ij * 64; }

  int rem = N - mbase;
  int nmt = rem >= 64 ? 4 : (rem >> 4);   // N multiple of 16

  f32x4 acc[4][4];
  #pragma unroll
  for (int a = 0; a < 4; a++)
    #pragma unroll
    for (int b = 0; b < 4; b++) acc[a][b] = (f32x4){0.f, 0.f, 0.f, 0.f};

  for (int ks = 0; ks < K; ks += 32) {
    sh8 bfrag[4];
    for (int nt = 0; nt < NT; nt++) {
      const unsigned short* wp = W + (size_t)(nt * 16 + col) * K + ks + quad * 8;
      bfrag[nt] = *(const sh8*)wp;
    }
    for (int mt = 0; mt < nmt; mt++) {
      const unsigned short* xp = X + (size_t)(mbase + mt * 16 + col) * K + ks + quad * 8;
      sh8 afrag = *(const sh8*)xp;
      for (int nt = 0; nt < NT; nt++)
        acc[mt][nt] = __builtin_amdgcn_mfma_f32_16x16x32_bf16(afrag, bfrag[nt], acc[mt][nt], 0, 0, 0);
    }
  }
  // C layout: col = lane&15 (output row), row = quad*4+reg (node within tile)
  for (int mt = 0; mt < nmt; mt++) {
    int m0 = mbase + mt * 16 + quad * 4;
    for (int nt = 0; nt < NT; nt++) {
      #pragma unroll
      for (int reg = 0; reg < 4; reg++)
        P[(size_t)(m0 + reg) * 816 + outbase + nt * 16 + col] = acc[mt][nt][reg];
    }
  }
}

// ------------------- CSR build ---------------------------------------------
__global__ void hist_kernel(const int* __restrict__ src, int* __restrict__ counts, int E) {
  int e = blockIdx.x * 256 + threadIdx.x;
  if (e < E) atomicAdd(&counts[src[e]], 1);
}

__global__ __launch_bounds__(1024) void scan_kernel(
    const int* __restrict__ counts, int* __restrict__ offs, int* __restrict__ cursor,
    int N, int E)
{
  __shared__ int part[1024];
  int tid = threadIdx.x;
  int chunk = (N + 1023) / 1024;
  int lo = tid * chunk, hi = min(lo + chunk, N);
  int s = 0;
  for (int i = lo; i < hi; i++) s += counts[i];
  part[tid] = s;
  __syncthreads();
  for (int off = 1; off < 1024; off <<= 1) {
    int v = (tid >= off) ? part[tid - off] : 0;
    __syncthreads();
    part[tid] += v;
    __syncthreads();
  }
  int run = part[tid] - s;
  for (int i = lo; i < hi; i++) { offs[i] = run; cursor[i] = run; run += counts[i]; }
  if (tid == 0) offs[N] = E;
}

__global__ void scatter_kernel(const int* __restrict__ src, int* __restrict__ cursor,
                               int* __restrict__ eidx, int E) {
  int e = blockIdx.x * 256 + threadIdx.x;
  if (e < E) { int p = atomicAdd(&cursor[src[e]], 1); eidx[p] = e; }
}

// ------------------- K2: one wave per node, atomic-free ---------------------
// LDS float map (1280):
//   [0,816)    sP  (gathered P[dst], NEW layout)
//   [816,992)  sq  (q[i*16+r], 176)
//   [992,996)  rvtab: rv0,rv1,rv2,1.0
//   [996,1005) outer[ij] = rv_i*rv_j
//   [1008,1264) edge meta float4[64]
// Epilogue reuses [0,960) as ACC (layout unchanged from R4).
__global__ __launch_bounds__(64, 3) void node_gather_kernel(
    const float* __restrict__ r_ij, const int* __restrict__ dst,
    const int* __restrict__ offs, const int* __restrict__ eidx,
    const float* __restrict__ Pg, const float* __restrict__ W2,
    const float* __restrict__ Wo_a, const float* __restrict__ Wo_v, const float* __restrict__ Wo_d,
    float* __restrict__ out, int N)
{
  __shared__ __align__(16) float S[1280];
  float4* S4 = (float4*)S;
  const int n = blockIdx.x, lane = threadIdx.x;
  const int off = offs[n], deg = offs[n + 1] - off;

  // ---- per-lane slot constants (V slots p=0..2, D slots p=3..11) ----
  // NEW P layout: Pa k*16+r | Pv 48+i*64+k*16+r | Pd 240+ij*64+k*16+r
  // dot3 slots (typm bit set) read S[a], S[a+64], S[a+128].
  int aP[12], aQ[12], aF[12];
  unsigned typm = 0;
  #pragma unroll
  for (int p = 0; p < 3; p++) {
    int t = lane + 64 * p;                 // < 192
    int k = t / 48, m = t - 48 * k, jj = m >> 4, r = m & 15;
    int q_ = 816 + (3 + k) * 16 + r;       // q3..q6
    int P_, F_;
    if (k == 0)      { P_ = 16 + r;                    F_ = 992 + jj; }            // tp_011: pa011 * rv_j
    else if (k == 1) { P_ = 48 + jj * 64 + r;          F_ = 995; }                 // tp_101: pv101(k=0,r,j)
    else if (k == 2) { P_ = 96 + r;                    F_ = 992 + jj; typm |= 1u << p; }  // tp_121: dot_i pv121(k=3)
    else             { P_ = 240 + (3 * jj) * 64 + 16 + r; F_ = 995;  typm |= 1u << p; }   // tp_211: dot_j pd211(k=1)
    aP[p] = P_; aQ[p] = q_; aF[p] = F_;
  }
  #pragma unroll
  for (int p = 0; p < 9; p++) {
    int u = lane + 64 * p;                 // < 576
    int s = u / 144, m = u - 144 * s, ij = m >> 4, r = m & 15;
    int i = ij / 3, jj = ij - 3 * i;
    int P_, F_, q_;
    if (s == 0)      { P_ = 32 + r;                     q_ = 112 + r; F_ = 996 + ij; }   // pa022 * outer
    else if (s == 1) { P_ = 48 + i * 64 + 32 + r;       q_ = 128 + r; F_ = 992 + jj; }   // pv112(k=2,r,i)*rv_j
    else if (s == 2) { P_ = 240 + ij * 64 + r;          q_ = 144 + r; F_ = 995; }        // pd202(k=0,r,ij)
    else             { P_ = 240 + (3 * i) * 64 + 48 + r; q_ = 160 + r; F_ = 992 + jj; typm |= 1u << (3 + p); } // dot_j pd222(k=3)
    aP[3 + p] = P_; aQ[3 + p] = 816 + q_; aF[3 + p] = F_;
  }
  const int ak = lane >> 4, ar = lane & 15;   // A slot (lane<48)

  // ---- hoist W2 rows for this lane's q slots ----
  float4 wqa[3], wqb[3];
  #pragma unroll
  for (int p = 0; p < 3; p++) {
    int tq = lane + 64 * p; if (tq > 175) tq = 175;
    const float4* w = (const float4*)(W2 + tq * 8);
    wqa[p] = w[0]; wqb[p] = w[1];
  }

  float accA = 0.0f, acc[12];
  #pragma unroll
  for (int p = 0; p < 12; p++) acc[p] = 0.0f;

  float4 pb0 = {}, pb1 = {}, pb2 = {}, pb3 = {};
  const int l3 = 192 + (lane < 12 ? lane : 0);

  for (int base = 0; base < deg; base += 64) {
    int cnt = min(deg - base, 64);
    __syncthreads();
    if (lane < cnt) {
      int e = eidx[off + base + lane];
      float a = r_ij[3 * (size_t)e], b = r_ij[3 * (size_t)e + 1], c = r_ij[3 * (size_t)e + 2];
      S4[252 + lane] = make_float4(a, b, c, __int_as_float(dst[e]));
    }
    __syncthreads();
    {
      float4 me = S4[252];
      if (me.x * me.x + me.y * me.y + me.z * me.z < 5.0f) {
        const float4* Pp = (const float4*)(Pg + (size_t)__float_as_int(me.w) * 816);
        pb0 = Pp[lane]; pb1 = Pp[64 + lane]; pb2 = Pp[128 + lane]; pb3 = Pp[l3];
      }
    }
    for (int t = 0; t < cnt; t++) {
      float4 me = S4[252 + t];
      float r0 = me.x, r1 = me.y, r2 = me.z;
      float rr = r0 * r0 + r1 * r1 + r2 * r2;
      bool live = rr < 5.0f;
      float rv0 = 0, rv1 = 0, rv2 = 0;
      if (live) {
        float x_sq = rr * (1.0f / R0_F);
        float env = 1.0f - x_sq;
        float v0 = r0 * (17.0f / R0_F), v1 = r1 * (17.0f / R0_F), v2 = r2 * (17.0f / R0_F);
        float nn = sqrtf(v0 * v0 + v1 * v1 + v2 * v2);
        float sig = 2.0f / (1.0f + __expf(-nn)) - 1.0f;
        float sc = sig / (nn + 1e-6f);
        rv0 = v0 * sc; rv1 = v1 * sc; rv2 = v2 * sc;
        float rad[8];
        {
          float c1 = __cosf(PI_F * sqrtf(x_sq));
          float two_c1 = 2.0f * c1, cm2 = 1.0f, cm1 = c1;
          rad[0] = env; rad[1] = c1 * env;
          #pragma unroll
          for (int k = 2; k < 8; k++) { float c = two_c1 * cm1 - cm2; rad[k] = c * env; cm2 = cm1; cm1 = c; }
        }
        float4 ra = make_float4(rad[0], rad[1], rad[2], rad[3]);
        float4 rb = make_float4(rad[4], rad[5], rad[6], rad[7]);
        S4[lane] = pb0; S4[64 + lane] = pb1; S4[128 + lane] = pb2;
        if (lane < 12) S4[192 + lane] = pb3;
        S[816 + lane] = dot4(wqa[0], ra) + dot4(wqb[0], rb);
        S[880 + lane] = dot4(wqa[1], ra) + dot4(wqb[1], rb);
        if (lane < 48) S[944 + lane] = dot4(wqa[2], ra) + dot4(wqb[2], rb);
        if (lane < 4) S[992 + lane] = (lane == 0) ? rv0 : (lane == 1) ? rv1 : (lane == 2) ? rv2 : 1.0f;
        if (lane >= 4 && lane < 13) {
          int ij = lane - 4, i = ij / 3, j = ij - 3 * i;
          float a = (i == 0) ? rv0 : (i == 1) ? rv1 : rv2;
          float b = (j == 0) ? rv0 : (j == 1) ? rv1 : rv2;
          S[992 + lane] = a * b;
        }
      }
      if (t + 1 < cnt) {
        float4 m2 = S4[252 + t + 1];
        if (m2.x * m2.x + m2.y * m2.y + m2.z * m2.z < 5.0f) {
          const float4* Pp = (const float4*)(Pg + (size_t)__float_as_int(m2.w) * 816);
          pb0 = Pp[lane]; pb1 = Pp[64 + lane]; pb2 = Pp[128 + lane]; pb3 = Pp[l3];
        }
      }
      __syncthreads();
      if (live) {
        if (lane < 48) {
          float v;
          if (ak == 0)      v = S[ar] * S[816 + ar];
          else if (ak == 1) {
            int b = 64 + ar;   // pv110(k=1,r,i) at 48+i*64+16+r
            v = (S[b] * rv0 + S[b + 64] * rv1 + S[b + 128] * rv2) * S[832 + ar];
          } else {
            int b = 272 + ar;  // pd220(k=2,r,ij) at 240+ij*64+32+r
            float o = 0.0f;
            #pragma unroll
            for (int ij = 0; ij < 9; ij++) o += S[b + 64 * ij] * S[996 + ij];
            v = o * S[848 + ar];
          }
          accA += v;
        }
        #pragma unroll
        for (int p = 0; p < 12; p++) {
          float pv;
          if (typm & (1u << p)) pv = S[aP[p]] * rv0 + S[aP[p] + 64] * rv1 + S[aP[p] + 128] * rv2;
          else                  pv = S[aP[p]];
          acc[p] += pv * S[aQ[p]] * S[aF[p]];
        }
      }
      __syncthreads();
    }
  }

  // ---------------- epilogue: rank->channel, write out ----------------
  __syncthreads();
  if (lane < 48) S[lane] = accA;
  #pragma unroll
  for (int p = 0; p < 3; p++) S[48 + lane + 64 * p] = acc[p];
  #pragma unroll
  for (int p = 0; p < 9; p++) {
    int u = lane + 64 * p;
    int s = u / 144, m = u - 144 * s, ij = m >> 4, r = m & 15;
    S[240 + s * 180 + ij * 20 + r] = acc[3 + p];
  }
  __syncthreads();

  const size_t baseV = (size_t)N * 128;
  const size_t baseD = (size_t)N * 320;

  #pragma unroll
  for (int h = 0; h < 2; h++) {
    int c = lane + 64 * h;
    float a_ = 0.0f;
    #pragma unroll
    for (int k = 0; k < 3; k++) {
      const float4* w = (const float4*)(Wo_a + k * 2048 + c * 16);
      const float4* A4 = (const float4*)(&S[k * 16]);
      #pragma unroll
      for (int cc = 0; cc < 4; cc++) a_ += dot4(w[cc], A4[cc]);
    }
    out[(size_t)n * 128 + c] = a_;
  }
  {
    float o0 = 0, o1 = 0, o2 = 0;
    #pragma unroll
    for (int k = 0; k < 4; k++) {
      const float4* w = (const float4*)(Wo_v + k * 1024 + lane * 16);
      float4 w0 = w[0], w1 = w[1], w2 = w[2], w3 = w[3];
      #pragma unroll
      for (int j = 0; j < 3; j++) {
        const float4* A4 = (const float4*)(&S[48 + k * 48 + j * 16]);
        float v = dot4(w0, A4[0]) + dot4(w1, A4[1]) + dot4(w2, A4[2]) + dot4(w3, A4[3]);
        if (j == 0) o0 += v; else if (j == 1) o1 += v; else o2 += v;
      }
    }
    size_t ov = baseV + (size_t)n * 192 + lane * 3;
    out[ov] = o0; out[ov + 1] = o1; out[ov + 2] = o2;
  }
  #pragma unroll
  for (int p = 0; p < 5; p++) {
    int t = lane + 64 * p;
    if (t < 288) {
      int d = t / 9, ij = t - 9 * d;
      float a_ = 0.0f;
      #pragma unroll
      for (int s = 0; s < 4; s++) {
        const float4* w = (const float4*)(Wo_d + s * 512 + d * 16);
        const float4* A4 = (const float4*)(&S[240 + s * 180 + ij * 20]);
        a_ += dot4(w[0], A4[0]) + dot4(w[1], A4[1]) + dot4(w[2], A4[2]) + dot4(w[3], A4[3]);
      }
      out[baseD + (size_t)n * 288 + t] = a_;
    }
  }
}

// ---------------------------------------------------------------------------
extern "C" void kernel_launch(void* const* d_in, const int* in_sizes, int n_in,
                              void* d_out, int out_size, void* d_ws, size_t ws_size,
                              hipStream_t stream) {
  const float* r_ij = (const float*)d_in[0];
  const float* x_a  = (const float*)d_in[1];
  const float* x_v  = (const float*)d_in[2];
  const float* x_d  = (const float*)d_in[3];
  const float* W1_a = (const float*)d_in[4];
  const float* W1_v = (const float*)d_in[5];
  const float* W1_d = (const float*)d_in[6];
  const float* W2   = (const float*)d_in[7];
  const float* Wo_a = (const float*)d_in[8];
  const float* Wo_v = (const float*)d_in[9];
  const float* Wo_d = (const float*)d_in[10];
  const int*  src   = (const int*)d_in[11];
  const int*  dst   = (const int*)d_in[12];

  const int E = in_sizes[0] / 3;
  const int N = in_sizes[1] / 128;

  float* P = (float*)d_ws;
  unsigned short* xa = (unsigned short*)(P + (size_t)N * 816);
  unsigned short* xv = xa + (size_t)N * 128;
  unsigned short* xd = xv + (size_t)N * 192;
  unsigned short* wb = xd + (size_t)N * 288;
  int* counts = (int*)(wb + 12288);
  int* offs   = counts + N;
  int* cursor = offs + N + 1;
  int* eidx   = cursor + N;

  hipMemsetAsync(counts, 0, sizeof(int) * (size_t)N, stream);

  hist_kernel<<<(E + 255) / 256, 256, 0, stream>>>(src, counts, E);
  scan_kernel<<<1, 1024, 0, stream>>>(counts, offs, cursor, N, E);
  scatter_kernel<<<(E + 255) / 256, 256, 0, stream>>>(src, cursor, eidx, E);

  repack_aw_kernel<<<(N * 128 + 12288 + 255) / 256, 256, 0, stream>>>(
      x_a, W1_a, W1_v, W1_d, xa, wb, N);
  repack_xv_kernel<<<dim3((N * 64 + 255) / 256, 3), 256, 0, stream>>>(x_v, xv, N);
  repack_xd_kernel<<<dim3((N * 32 + 255) / 256, 9), 256, 0, stream>>>(x_d, xd, N);
  mfma_proj_kernel<<<dim3((N + 63) / 64, 13), 64, 0, stream>>>(xa, xv, xd, wb, P, N);

  node_gather_kernel<<<N, 64, 0, stream>>>(r_ij, dst, offs, eidx, P, W2,
                                           Wo_a, Wo_v, Wo_d, (float*)d_out, N);
}